// Round 1
// baseline (588.717 us; speedup 1.0000x reference)
//
#include <hip/hip_runtime.h>
#include <cstdint>

#define TILE 64
#define BK   16
#define PAD  4     // 64+4 = 68 floats -> 272B row stride, 16B aligned for float4

#define HEADS 12
#define DH    64
#define NSEQ  1024
#define CEMB  768

// ---------------------------------------------------------------------------
// C[M,N] = A[M,K] @ B[K,N] + bias[N]
// 64x64 block tile, 256 threads, 4x4 per thread, BK=16
// ---------------------------------------------------------------------------
__global__ __launch_bounds__(256) void gemm_bias_f32(
    const float* __restrict__ A, const float* __restrict__ B,
    const float* __restrict__ bias, float* __restrict__ C,
    int M, int N, int K)
{
    __shared__ float As[BK][TILE + PAD];   // As[k][m]  (A transposed in LDS)
    __shared__ float Bs[BK][TILE + PAD];   // Bs[k][n]

    const int tid = threadIdx.x;
    const int tx  = tid & 15;
    const int ty  = tid >> 4;
    const int bn  = blockIdx.x * TILE;
    const int bm  = blockIdx.y * TILE;

    const int a_m  = tid >> 2;         // 0..63  (row in tile)
    const int a_k0 = (tid & 3) * 4;    // 0,4,8,12
    const int b_k  = tid >> 4;         // 0..15
    const int b_n  = (tid & 15) * 4;   // 0..60

    float acc[4][4] = {};

    for (int k0 = 0; k0 < K; k0 += BK) {
        float4 av = *(const float4*)&A[(size_t)(bm + a_m) * K + k0 + a_k0];
        As[a_k0 + 0][a_m] = av.x;
        As[a_k0 + 1][a_m] = av.y;
        As[a_k0 + 2][a_m] = av.z;
        As[a_k0 + 3][a_m] = av.w;
        *(float4*)&Bs[b_k][b_n] =
            *(const float4*)&B[(size_t)(k0 + b_k) * N + bn + b_n];
        __syncthreads();

        #pragma unroll
        for (int kk = 0; kk < BK; ++kk) {
            float4 a4 = *(const float4*)&As[kk][ty * 4];
            float4 b4 = *(const float4*)&Bs[kk][tx * 4];
            float ar[4] = {a4.x, a4.y, a4.z, a4.w};
            float br[4] = {b4.x, b4.y, b4.z, b4.w};
            #pragma unroll
            for (int i = 0; i < 4; ++i)
                #pragma unroll
                for (int j = 0; j < 4; ++j)
                    acc[i][j] = fmaf(ar[i], br[j], acc[i][j]);
        }
        __syncthreads();
    }

    #pragma unroll
    for (int i = 0; i < 4; ++i) {
        const int row = bm + ty * 4 + i;
        float4 o;
        o.x = acc[i][0] + bias[bn + tx * 4 + 0];
        o.y = acc[i][1] + bias[bn + tx * 4 + 1];
        o.z = acc[i][2] + bias[bn + tx * 4 + 2];
        o.w = acc[i][3] + bias[bn + tx * 4 + 3];
        *(float4*)&C[(size_t)row * N + bn + tx * 4] = o;
    }
}

// ---------------------------------------------------------------------------
// Flash attention over the interleaved qkv buffer (B,N,3C) where column
// (h*64+d)*3 + {0,1,2} selects q/k/v.  One block = one (b,h) x 64 q-rows.
// Output written as (B,N,C) with C = [h][d] so proj GEMM reads it flat.
// ---------------------------------------------------------------------------
__global__ __launch_bounds__(256) void attn_flash_f32(
    const float* __restrict__ qkv, float* __restrict__ out)
{
    __shared__ float Qs[DH][TILE + PAD];    // [d][q_row], pre-scaled
    __shared__ float Ks[DH][TILE + PAD];    // [d][k_col]
    __shared__ float Vs[TILE][DH + PAD];    // [key][d]
    __shared__ float Ps[TILE][TILE + PAD];  // [key][q_row]

    const int tid = threadIdx.x;
    const int tx  = tid & 15;
    const int ty  = tid >> 4;
    const int bh  = blockIdx.y;
    const int b   = bh / HEADS;
    const int h   = bh % HEADS;
    const int n0  = blockIdx.x * TILE;

    const float scale = 0.03608439182435161f;  // 1/sqrt(768)  (per source!)

    // load Q tile, pre-scaled, transposed into [d][row]
    #pragma unroll
    for (int it = 0; it < 16; ++it) {
        int idx = it * 256 + tid;
        int r = idx >> 6;
        int c = idx & 63;
        size_t g = (size_t)(b * NSEQ + n0 + r) * (3 * CEMB) + (size_t)(h * DH + c) * 3;
        Qs[c][r] = qkv[g] * scale;
    }

    float m[4], l[4], o[4][4];
    #pragma unroll
    for (int i = 0; i < 4; ++i) {
        m[i] = -1e30f;
        l[i] = 0.0f;
        #pragma unroll
        for (int j = 0; j < 4; ++j) o[i][j] = 0.0f;
    }

    for (int j0 = 0; j0 < NSEQ; j0 += TILE) {
        // load K (transposed) and V (natural) tiles
        #pragma unroll
        for (int it = 0; it < 16; ++it) {
            int idx = it * 256 + tid;
            int r = idx >> 6;
            int c = idx & 63;
            size_t g = (size_t)(b * NSEQ + j0 + r) * (3 * CEMB) + (size_t)(h * DH + c) * 3;
            Ks[c][r] = qkv[g + 1];
            Vs[r][c] = qkv[g + 2];
        }
        __syncthreads();

        // S = Q K^T  (64x64, each thread 4x4)
        float s[4][4] = {};
        #pragma unroll
        for (int dd = 0; dd < DH; ++dd) {
            float4 q4 = *(const float4*)&Qs[dd][ty * 4];
            float4 k4 = *(const float4*)&Ks[dd][tx * 4];
            float qr[4] = {q4.x, q4.y, q4.z, q4.w};
            float kr[4] = {k4.x, k4.y, k4.z, k4.w};
            #pragma unroll
            for (int i = 0; i < 4; ++i)
                #pragma unroll
                for (int j = 0; j < 4; ++j)
                    s[i][j] = fmaf(qr[i], kr[j], s[i][j]);
        }

        // online softmax: row reductions across the 16-lane tx group
        float rmax[4], mn[4], corr[4], rsum[4];
        #pragma unroll
        for (int i = 0; i < 4; ++i) {
            float v = fmaxf(fmaxf(s[i][0], s[i][1]), fmaxf(s[i][2], s[i][3]));
            #pragma unroll
            for (int off = 1; off < 16; off <<= 1)
                v = fmaxf(v, __shfl_xor(v, off));
            rmax[i] = v;
            mn[i]   = fmaxf(m[i], rmax[i]);
            corr[i] = __expf(m[i] - mn[i]);
            m[i]    = mn[i];
        }

        float p[4][4];
        #pragma unroll
        for (int i = 0; i < 4; ++i) {
            float rs = 0.0f;
            #pragma unroll
            for (int j = 0; j < 4; ++j) {
                p[i][j] = __expf(s[i][j] - mn[i]);
                rs += p[i][j];
            }
            #pragma unroll
            for (int off = 1; off < 16; off <<= 1)
                rs += __shfl_xor(rs, off);
            rsum[i] = rs;
            l[i] = l[i] * corr[i] + rsum[i];
            #pragma unroll
            for (int j = 0; j < 4; ++j) o[i][j] *= corr[i];
        }

        // stage P transposed: Ps[key][q_row]
        #pragma unroll
        for (int j = 0; j < 4; ++j) {
            float4 pv = make_float4(p[0][j], p[1][j], p[2][j], p[3][j]);
            *(float4*)&Ps[tx * 4 + j][ty * 4] = pv;
        }
        __syncthreads();

        // O += P @ V   (o[i][j]: q_row ty*4+i, dim tx*4+j)
        #pragma unroll
        for (int kk = 0; kk < TILE; ++kk) {
            float4 p4 = *(const float4*)&Ps[kk][ty * 4];
            float4 v4 = *(const float4*)&Vs[kk][tx * 4];
            float pr[4] = {p4.x, p4.y, p4.z, p4.w};
            float vr[4] = {v4.x, v4.y, v4.z, v4.w};
            #pragma unroll
            for (int i = 0; i < 4; ++i)
                #pragma unroll
                for (int j = 0; j < 4; ++j)
                    o[i][j] = fmaf(pr[i], vr[j], o[i][j]);
        }
        __syncthreads();
    }

    // epilogue: normalize and store to (B,N,C) with col = h*64 + d
    #pragma unroll
    for (int i = 0; i < 4; ++i) {
        const float inv = 1.0f / l[i];
        const int row = n0 + ty * 4 + i;
        float4 ov = make_float4(o[i][0] * inv, o[i][1] * inv,
                                o[i][2] * inv, o[i][3] * inv);
        *(float4*)&out[(size_t)(b * NSEQ + row) * CEMB + h * DH + tx * 4] = ov;
    }
}

// ---------------------------------------------------------------------------
extern "C" void kernel_launch(void* const* d_in, const int* in_sizes, int n_in,
                              void* d_out, int out_size, void* d_ws, size_t ws_size,
                              hipStream_t stream)
{
    const float* x      = (const float*)d_in[0];   // (4,1024,768)
    const float* w_qkv  = (const float*)d_in[1];   // (768,2304)
    const float* b_qkv  = (const float*)d_in[2];   // (2304,)
    const float* w_proj = (const float*)d_in[3];   // (768,768)
    const float* b_proj = (const float*)d_in[4];   // (768,)
    float*       outp   = (float*)d_out;           // (4,1024,768)

    float* qkv     = (float*)d_ws;                          // 4096*2304 f32
    float* attnout = qkv + (size_t)4096 * 2304;             // 4096*768  f32

    const int M = 4096;  // B*N

    // 1) qkv = x @ w_qkv + b_qkv
    gemm_bias_f32<<<dim3(2304 / TILE, M / TILE), 256, 0, stream>>>(
        x, w_qkv, b_qkv, qkv, M, 2304, 768);

    // 2) flash attention -> attnout (B,N,C)
    attn_flash_f32<<<dim3(NSEQ / TILE, 4 * HEADS), 256, 0, stream>>>(
        qkv, attnout);

    // 3) out = attnout @ w_proj + b_proj
    gemm_bias_f32<<<dim3(CEMB / TILE, M / TILE), 256, 0, stream>>>(
        attnout, w_proj, b_proj, outp, M, CEMB, 768);
}

// Round 2
// 95.638 us; speedup vs baseline: 6.1557x; 6.1557x over previous
//
#include <hip/hip_runtime.h>
#include <cstdint>

typedef __attribute__((ext_vector_type(8))) short short8;
typedef __attribute__((ext_vector_type(4))) short short4v;
typedef __attribute__((ext_vector_type(4))) float f32x4;
typedef unsigned short ushort_t;

#define MFMA(a, b, c) __builtin_amdgcn_mfma_f32_16x16x32_bf16(a, b, c, 0, 0, 0)

__device__ __forceinline__ ushort_t f2bf(float f) {
    unsigned u = __float_as_uint(f);
    u += 0x7FFF + ((u >> 16) & 1);      // round-to-nearest-even
    return (ushort_t)(u >> 16);
}

__device__ __forceinline__ void gld_lds16(const ushort_t* g, ushort_t* l) {
    __builtin_amdgcn_global_load_lds(
        (__attribute__((address_space(1))) void*)g,
        (__attribute__((address_space(3))) void*)l, 16, 0, 0);
}

// ---------------------------------------------------------------------------
// elementwise f32 -> bf16  (n multiple of 8)
// ---------------------------------------------------------------------------
__global__ __launch_bounds__(256) void cvt_bf(const float* __restrict__ in,
                                              ushort_t* __restrict__ out, int n) {
    int i = (blockIdx.x * 256 + threadIdx.x) * 8;
    if (i >= n) return;
    float4 a = *(const float4*)&in[i];
    float4 b = *(const float4*)&in[i + 4];
    uint4 v;
    v.x = f2bf(a.x) | (f2bf(a.y) << 16);
    v.y = f2bf(a.z) | (f2bf(a.w) << 16);
    v.z = f2bf(b.x) | (f2bf(b.y) << 16);
    v.w = f2bf(b.z) | (f2bf(b.w) << 16);
    *(uint4*)&out[i] = v;
}

// ---------------------------------------------------------------------------
// weight transpose (+optional qkv column permute & q-scale):
//   out[jp][k] = w[k][j] * s,  jp = perm(j)
// mode 0: qkv (j -> which*768 + h*64 + d, scale q cols); mode 1: identity
// ---------------------------------------------------------------------------
__global__ __launch_bounds__(256) void wtrans(const float* __restrict__ w,
                                              ushort_t* __restrict__ out,
                                              int K, int J, int mode, float scale) {
    __shared__ float t[64][68];
    const int k0 = blockIdx.y * 64, j0 = blockIdx.x * 64;
    for (int g = threadIdx.x; g < 1024; g += 256) {
        int r = g >> 4, c4 = g & 15;
        float4 v = *(const float4*)&w[(size_t)(k0 + r) * J + j0 + c4 * 4];
        *(float4*)&t[r][c4 * 4] = v;
    }
    __syncthreads();
    const int jj = threadIdx.x >> 2, kc = threadIdx.x & 3;
    const int j = j0 + jj;
    int jp; float s;
    if (mode == 0) {
        int which = j % 3, hh = j / 192, d = (j % 192) / 3;
        jp = which * 768 + hh * 64 + d;
        s = (which == 0) ? scale : 1.f;
    } else { jp = j; s = 1.f; }
    ushort_t o[16];
    #pragma unroll
    for (int i = 0; i < 16; ++i) o[i] = f2bf(t[kc * 16 + i][jj] * s);
    uint4 v0, v1;
    v0.x = o[0] | (o[1] << 16);  v0.y = o[2] | (o[3] << 16);
    v0.z = o[4] | (o[5] << 16);  v0.w = o[6] | (o[7] << 16);
    v1.x = o[8] | (o[9] << 16);  v1.y = o[10] | (o[11] << 16);
    v1.z = o[12] | (o[13] << 16); v1.w = o[14] | (o[15] << 16);
    *(uint4*)&out[(size_t)jp * K + k0 + kc * 16] = v0;
    *(uint4*)&out[(size_t)jp * K + k0 + kc * 16 + 8] = v1;
}

__global__ void bias_perm(const float* __restrict__ bq, float* __restrict__ out,
                          float scale) {
    int j = blockIdx.x * 256 + threadIdx.x;
    if (j < 2304) {
        int which = j % 3, hh = j / 192, d = (j % 192) / 3;
        out[which * 768 + hh * 64 + d] = bq[j] * (which == 0 ? scale : 1.f);
    }
}

// ---------------------------------------------------------------------------
// V transpose: Vt[bh][d][n] = qkv[b*1024+n][1536 + h*64 + d]
// ---------------------------------------------------------------------------
__global__ __launch_bounds__(256) void vtrans(const ushort_t* __restrict__ qkv,
                                              ushort_t* __restrict__ Vt) {
    __shared__ ushort_t t[64][72];
    const int bh = blockIdx.y, b = bh / 12, h = bh % 12;
    const int n0 = blockIdx.x * 64;
    for (int g = threadIdx.x; g < 512; g += 256) {
        int r = g >> 3, c8 = g & 7;
        uint4 v = *(const uint4*)&qkv[(size_t)(b * 1024 + n0 + r) * 2304 + 1536 + h * 64 + c8 * 8];
        *(uint4*)&t[r][c8 * 8] = v;
    }
    __syncthreads();
    for (int g = threadIdx.x; g < 512; g += 256) {
        int d = g >> 3, n8 = g & 7;
        ushort_t o[8];
        #pragma unroll
        for (int i = 0; i < 8; ++i) o[i] = t[n8 * 8 + i][d];
        uint4 v;
        v.x = o[0] | (o[1] << 16); v.y = o[2] | (o[3] << 16);
        v.z = o[4] | (o[5] << 16); v.w = o[6] | (o[7] << 16);
        *(uint4*)&Vt[(size_t)bh * 65536 + (size_t)d * 1024 + n0 + n8 * 8] = v;
    }
}

// ---------------------------------------------------------------------------
// C[M,N] = A[M,K] @ Bt[N,K]^T + bias  (bf16 in, fp32 acc, bf16/f32 out)
// 128x128 tile, BK=64, 4 waves, 4x4 16x16x32 MFMA tiles per wave.
// LDS XOR-swizzled via pre-swizzled global source for global_load_lds.
// ---------------------------------------------------------------------------
template <int OUT_BF16>
__global__ __launch_bounds__(256, 2) void gemm_mfma(
    const ushort_t* __restrict__ A, const ushort_t* __restrict__ Bt,
    const float* __restrict__ bias, void* __restrict__ Cout,
    int M, int N, int K) {
    __shared__ ushort_t As[128 * 64];
    __shared__ ushort_t Bs[128 * 64];

    const int tid = threadIdx.x;
    const int lane = tid & 63;
    const int wv = tid >> 6;
    const int wr = wv >> 1, wc = wv & 1;
    const int l15 = lane & 15;
    const int lg = lane >> 4;

    const int m0 = blockIdx.y * 128;
    const int n0 = blockIdx.x * 128;

    const int rbase = tid >> 3;        // 0..31
    const int c8l = tid & 7;
    const int swz8 = (c8l ^ (rbase & 7)) * 8;   // bf16 elems

    const ushort_t* gA = A + (size_t)(m0 + rbase) * K + swz8;
    const ushort_t* gB = Bt + (size_t)(n0 + rbase) * K + swz8;
    ushort_t* lA = As + tid * 8;
    ushort_t* lB = Bs + tid * 8;

    f32x4 acc[4][4];
    #pragma unroll
    for (int i = 0; i < 4; ++i)
        #pragma unroll
        for (int j = 0; j < 4; ++j) acc[i][j] = (f32x4){0.f, 0.f, 0.f, 0.f};

    for (int k0 = 0; k0 < K; k0 += 64) {
        #pragma unroll
        for (int rr = 0; rr < 4; ++rr) {
            gld_lds16(gA + (size_t)rr * 32 * K + k0, lA + rr * 2048);
            gld_lds16(gB + (size_t)rr * 32 * K + k0, lB + rr * 2048);
        }
        __syncthreads();

        #pragma unroll
        for (int kk = 0; kk < 2; ++kk) {
            short8 af[4], bfr[4];
            #pragma unroll
            for (int mt = 0; mt < 4; ++mt) {
                int row = wr * 64 + mt * 16 + l15;
                int gr = (kk * 4 + lg) ^ (row & 7);
                af[mt] = *(const short8*)&As[row * 64 + gr * 8];
            }
            #pragma unroll
            for (int nt = 0; nt < 4; ++nt) {
                int row = wc * 64 + nt * 16 + l15;
                int gr = (kk * 4 + lg) ^ (row & 7);
                bfr[nt] = *(const short8*)&Bs[row * 64 + gr * 8];
            }
            #pragma unroll
            for (int mt = 0; mt < 4; ++mt)
                #pragma unroll
                for (int nt = 0; nt < 4; ++nt)
                    acc[mt][nt] = MFMA(af[mt], bfr[nt], acc[mt][nt]);
        }
        __syncthreads();
    }

    #pragma unroll
    for (int nt = 0; nt < 4; ++nt) {
        int col = n0 + wc * 64 + nt * 16 + l15;
        float bb = bias[col];
        #pragma unroll
        for (int mt = 0; mt < 4; ++mt) {
            int row = m0 + wr * 64 + mt * 16 + lg * 4;
            #pragma unroll
            for (int r = 0; r < 4; ++r) {
                float v = acc[mt][nt][r] + bb;
                if (OUT_BF16)
                    ((ushort_t*)Cout)[(size_t)(row + r) * N + col] = f2bf(v);
                else
                    ((float*)Cout)[(size_t)(row + r) * N + col] = v;
            }
        }
    }
}

// ---------------------------------------------------------------------------
// Flash attention, bf16 MFMA.  Block: (q-tile 64) x (b,h).  4 waves, each
// owns 16 q rows.  Swapped QK^T (S^T = K.Q^T) keeps softmax lane-local per q.
// ---------------------------------------------------------------------------
__global__ __launch_bounds__(256, 2) void attn_mfma(
    const ushort_t* __restrict__ qkv,   // (4096, 2304) planar [Q|K|V]
    const ushort_t* __restrict__ Vt,    // (48, 64, 1024)
    ushort_t* __restrict__ outp) {      // (4096, 768)
    __shared__ ushort_t Qs[64 * 64];
    __shared__ ushort_t Ks[64 * 64];
    __shared__ ushort_t Vs[64 * 64];
    __shared__ ushort_t Ps[4][16 * 64];

    const int tid = threadIdx.x;
    const int lane = tid & 63;
    const int wv = tid >> 6;
    const int l15 = lane & 15;
    const int lg = lane >> 4;

    const int bh = blockIdx.y;
    const int b = bh / 12, h = bh % 12;
    const int q0 = blockIdx.x * 64;

    const int rbase = tid >> 3;
    const int c8l = tid & 7;
    const int swz8 = (c8l ^ (rbase & 7)) * 8;

    const ushort_t* gQ = qkv + (size_t)(b * 1024 + q0 + rbase) * 2304 + h * 64 + swz8;
    const ushort_t* gK = qkv + (size_t)(b * 1024 + rbase) * 2304 + 768 + h * 64 + swz8;
    const ushort_t* gV = Vt + (size_t)bh * 65536 + (size_t)rbase * 1024 + swz8;

    gld_lds16(gQ, Qs + tid * 8);
    gld_lds16(gQ + (size_t)32 * 2304, Qs + tid * 8 + 2048);
    __syncthreads();

    short8 bq[2];
    {
        int row = wv * 16 + l15;
        #pragma unroll
        for (int kk = 0; kk < 2; ++kk) {
            int gr = (kk * 4 + lg) ^ (row & 7);
            bq[kk] = *(const short8*)&Qs[row * 64 + gr * 8];
        }
    }

    float m_run = -1e30f, l_run = 0.f;
    f32x4 o[4];
    #pragma unroll
    for (int dt = 0; dt < 4; ++dt) o[dt] = (f32x4){0.f, 0.f, 0.f, 0.f};

    for (int kt = 0; kt < 16; ++kt) {
        gld_lds16(gK + (size_t)(kt * 64) * 2304, Ks + tid * 8);
        gld_lds16(gK + (size_t)(kt * 64 + 32) * 2304, Ks + tid * 8 + 2048);
        gld_lds16(gV + kt * 64, Vs + tid * 8);
        gld_lds16(gV + kt * 64 + 32 * 1024, Vs + tid * 8 + 2048);
        __syncthreads();

        // S^T = K . Q^T   (rows = 64 keys, cols = this wave's 16 q)
        f32x4 s[4];
        #pragma unroll
        for (int st = 0; st < 4; ++st) {
            int row = st * 16 + l15;
            int g0 = (0 + lg) ^ (row & 7);
            int g1 = (4 + lg) ^ (row & 7);
            short8 a0 = *(const short8*)&Ks[row * 64 + g0 * 8];
            short8 a1 = *(const short8*)&Ks[row * 64 + g1 * 8];
            f32x4 z = (f32x4){0.f, 0.f, 0.f, 0.f};
            z = MFMA(a0, bq[0], z);
            z = MFMA(a1, bq[1], z);
            s[st] = z;
        }

        // online softmax per q (= l15 column); lane holds keys st*16+lg*4+r
        float mloc = -1e30f;
        #pragma unroll
        for (int st = 0; st < 4; ++st)
            #pragma unroll
            for (int r = 0; r < 4; ++r) mloc = fmaxf(mloc, s[st][r]);
        mloc = fmaxf(mloc, __shfl_xor(mloc, 16));
        mloc = fmaxf(mloc, __shfl_xor(mloc, 32));
        float mnew = fmaxf(m_run, mloc);
        float corr = __expf(m_run - mnew);
        float psum = 0.f;
        #pragma unroll
        for (int st = 0; st < 4; ++st)
            #pragma unroll
            for (int r = 0; r < 4; ++r) {
                float p = __expf(s[st][r] - mnew);
                s[st][r] = p;
                psum += p;
            }
        psum += __shfl_xor(psum, 16);
        psum += __shfl_xor(psum, 32);
        l_run = l_run * corr + psum;
        m_run = mnew;
        #pragma unroll
        for (int dt = 0; dt < 4; ++dt)
            #pragma unroll
            for (int r = 0; r < 4; ++r) o[dt][r] *= corr;

        // stage P^T (16 q rows x 64 keys, bf16, swizzled) in wave-private LDS
        ushort_t* pb = Ps[wv];
        #pragma unroll
        for (int st = 0; st < 4; ++st) {
            int g8 = st * 2 + (lg >> 1);
            int byteoff = l15 * 128 + ((g8 ^ (l15 & 7)) * 16) + (lg & 1) * 8;
            short4v pv = {(short)f2bf(s[st][0]), (short)f2bf(s[st][1]),
                          (short)f2bf(s[st][2]), (short)f2bf(s[st][3])};
            *(short4v*)((char*)pb + byteoff) = pv;
        }

        // O^T += V^T . P^T  (rows = d, cols = q)
        #pragma unroll
        for (int kk = 0; kk < 2; ++kk) {
            int grp = (kk * 4 + lg) ^ (l15 & 7);
            short8 bp = *(const short8*)&pb[l15 * 64 + grp * 8];
            #pragma unroll
            for (int dt = 0; dt < 4; ++dt) {
                int row = dt * 16 + l15;
                int ga = (kk * 4 + lg) ^ (row & 7);
                short8 av = *(const short8*)&Vs[row * 64 + ga * 8];
                o[dt] = MFMA(av, bp, o[dt]);
            }
        }
        __syncthreads();
    }

    const float inv = 1.f / l_run;
    const int qrow = b * 1024 + q0 + wv * 16 + l15;
    #pragma unroll
    for (int dt = 0; dt < 4; ++dt)
        #pragma unroll
        for (int r = 0; r < 4; ++r) {
            int d = dt * 16 + lg * 4 + r;
            outp[(size_t)qrow * 768 + h * 64 + d] = f2bf(o[dt][r] * inv);
        }
}

// ---------------------------------------------------------------------------
extern "C" void kernel_launch(void* const* d_in, const int* in_sizes, int n_in,
                              void* d_out, int out_size, void* d_ws, size_t ws_size,
                              hipStream_t stream) {
    const float* x = (const float*)d_in[0];
    const float* w_qkv = (const float*)d_in[1];
    const float* b_qkv = (const float*)d_in[2];
    const float* w_proj = (const float*)d_in[3];
    const float* b_proj = (const float*)d_in[4];
    float* outp = (float*)d_out;

    char* ws = (char*)d_ws;
    ushort_t* x_bf = (ushort_t*)ws;   ws += (size_t)4096 * 768 * 2;
    ushort_t* wqT = (ushort_t*)ws;    ws += (size_t)2304 * 768 * 2;
    ushort_t* wpT = (ushort_t*)ws;    ws += (size_t)768 * 768 * 2;
    float* bq_p = (float*)ws;         ws += (size_t)2304 * 4;
    ushort_t* qkv_bf = (ushort_t*)ws; ws += (size_t)4096 * 2304 * 2;
    ushort_t* Vt = (ushort_t*)ws;     ws += (size_t)48 * 64 * 1024 * 2;
    ushort_t* aout = (ushort_t*)ws;

    const float scale = 0.036084391824351615f;  // 1/sqrt(768)

    cvt_bf<<<(4096 * 768) / (256 * 8), 256, 0, stream>>>(x, x_bf, 4096 * 768);
    wtrans<<<dim3(2304 / 64, 768 / 64), 256, 0, stream>>>(w_qkv, wqT, 768, 2304, 0, scale);
    wtrans<<<dim3(768 / 64, 768 / 64), 256, 0, stream>>>(w_proj, wpT, 768, 768, 1, 1.f);
    bias_perm<<<9, 256, 0, stream>>>(b_qkv, bq_p, scale);

    gemm_mfma<1><<<dim3(2304 / 128, 4096 / 128), 256, 0, stream>>>(
        x_bf, wqT, bq_p, qkv_bf, 4096, 2304, 768);

    vtrans<<<dim3(16, 48), 256, 0, stream>>>(qkv_bf, Vt);

    attn_mfma<<<dim3(16, 48), 256, 0, stream>>>(qkv_bf, Vt, aout);

    gemm_mfma<0><<<dim3(768 / 128, 4096 / 128), 256, 0, stream>>>(
        aout, wpT, b_proj, outp, 4096, 768, 768);
}